// Round 15
// baseline (859.850 us; speedup 1.0000x reference)
//
#include <hip/hip_runtime.h>

typedef unsigned short u16;
typedef unsigned int u32;
typedef __attribute__((ext_vector_type(8))) u16 u16x8;
typedef __attribute__((ext_vector_type(8))) __bf16 bf16x8;
typedef __attribute__((ext_vector_type(4))) float f32x4;

__device__ __forceinline__ float b2f(u16 u){ return __uint_as_float(((u32)u)<<16); }
__device__ __forceinline__ u16 f2b(float f){
  u32 b = __float_as_uint(f);
  return (u16)((b + 0x7fffu + ((b>>16)&1u))>>16);
}
__device__ __forceinline__ void gload16(const void* g, void* l){
  __builtin_amdgcn_global_load_lds((__attribute__((address_space(1))) void*)g,
                                   (__attribute__((address_space(3))) void*)l, 16, 0, 0);
}
__device__ __forceinline__ float wred_max(float v){
#pragma unroll
  for (int o=32;o>0;o>>=1) v = fmaxf(v, __shfl_xor(v,o));
  return v;
}
__device__ __forceinline__ float wred_sum(float v){
#pragma unroll
  for (int o=32;o>0;o>>=1) v += __shfl_xor(v,o);
  return v;
}

// out1 column order (set by W1T permutation in k_pre):
//   [0,512)   : vq (original order)
//   512+h*128 : head h's vk(64) | vv(64)  -- K+V contiguous 256B per key row
// so agent attention reads one dense 256B chunk per (key,head).

// ---- fused preprocessing: cast x -> bf16 | weight transposes | agent qkv ----
// grid 6384 x 256: [0,2048) cast, [2048,6144) prep_w, [6144,6384) agent qkv
__global__ void k_pre(const float* __restrict__ x, const float* __restrict__ wvq,
                      const float* __restrict__ wvkv, const float* __restrict__ wout,
                      const float* __restrict__ waqkv,
                      u16* __restrict__ xb, u16* __restrict__ W1T,
                      u16* __restrict__ WoutT, float* __restrict__ aqkv){
  const int bid = blockIdx.x, tid = threadIdx.x;
  if (bid < 2048){
    const int stride = 2048*256;
    for (int i = bid*256 + tid; i < 8030720; i += stride){
      const float4* p = (const float4*)(x + (size_t)i*8);
      float4 a = p[0], b = p[1];
      u16x8 o;
      o[0]=f2b(a.x); o[1]=f2b(a.y); o[2]=f2b(a.z); o[3]=f2b(a.w);
      o[4]=f2b(b.x); o[5]=f2b(b.y); o[6]=f2b(b.z); o[7]=f2b(b.w);
      *(u16x8*)(xb + (size_t)i*8) = o;
    }
  } else if (bid < 6144){
    int id = (bid-2048)*256 + tid;   // [0, 1048576)
    if (id < 786432){
      int n = id >> 9, k = id & 511;
      float v;
      if (n < 512){
        v = wvq[k*512 + n];
      } else {
        int j = n - 512, h = j >> 7, r = j & 127;
        int c2 = (r < 64) ? (h*64 + r) : (512 + h*64 + (r - 64));   // vk | vv
        v = wvkv[k*1024 + c2];
      }
      W1T[id] = f2b(v);
    } else {
      int j = id - 786432;
      int n = j >> 9, k = j & 511;
      WoutT[j] = f2b(wout[k*512 + n]);
    }
  } else {
    int id = (bid-6144)*256 + tid;   // [0, 61440)
    int bt = id / 1536, c = id % 1536;
    const float* xr = x + (size_t)bt*3137*512;
    float s = 0.f;
    for (int k=0;k<512;k++) s += xr[k]*waqkv[k*1536+c];
    aqkv[id] = s;
  }
}

// ---- 256x128 GEMM, 3-slot BK=32 ring, counted vmcnt, 2 blocks/CU ----
// A: MxK bf16 row-major, BT: NxK bf16 row-major. C = A * BT^T.
// Same sync structure as the r7-proven ring (one barrier/slot, stage into the
// slot freed at s-1, vmcnt never 0 mid-loop), tile halved so LDS = 72KB ->
// TWO co-resident blocks/CU: one block's epilogue/prologue overlaps the
// other's K-loop (r7 ran 1 block/CU; all pipes measured <=25% busy).
// Fragment-major LDS: every ds_read_b128 is uniform_base + lane*16 (0 conflicts).
// vmcnt ledger (3 loads/STAGE): at slot s outstanding = {s:3, s+1:3} ->
// vmcnt(3) proves s landed; tail vmcnt(0). Overwrite pos (s+2)%3 = (s-1)%3,
// whose readers drained (lgkm0) before this barrier.
// Plain epilogue only (nt = 2x write amp r4; routed/head-major +60us r11/r12).
template<int FOUT>
__global__ __launch_bounds__(512, 4) void k_gemm(
    const u16* __restrict__ A, const u16* __restrict__ BT,
    int M, int N, int K, int NX,
    u16* __restrict__ Cb, float* __restrict__ Cf, const float* __restrict__ bias)
{
  __shared__ __align__(16) char Ls[3][24576];   // slot: A 16KB | B 8KB
  const int tid = threadIdx.x;
  const int wid = tid >> 6, lane = tid & 63;
  // XCD-bijective swizzle (m204), n-fast work order (FETCH 512->81MB verified)
  const int nwg = gridDim.x, orig = blockIdx.x;
  const int q8 = nwg >> 3, r8 = nwg & 7;
  const int xc = orig & 7, sl = orig >> 3;
  const int work = (xc < r8 ? xc*(q8+1) : r8*(q8+1) + (xc-r8)*q8) + sl;
  const int m0 = (work / NX) * 256, n0 = (work % NX) * 128;
  const size_t K2 = (size_t)K * 2;
  const char* Ab = (const char*)A;
  const char* Bb = (const char*)BT;
  size_t asrc[2], bsrc;
  const int ad0 = wid*1024, ad1 = 8192 + wid*1024;  // wave-uniform LDS dest bases
  const int bd  = 16384 + wid*1024;
  {
    const int koff = (lane >> 4) << 4;
#pragma unroll
    for (int i=0;i<2;i++){
      int ra = m0 + (i*8 + wid)*16 + (lane & 15);
      if (ra >= M) ra = M - 1;                     // clamp partial last M-tile
      asrc[i] = (size_t)ra * K2 + koff;
    }
    bsrc = (size_t)(n0 + wid*16 + (lane & 15)) * K2 + koff;  // N multiple of 128
  }
#define STAGE(s3, ks) { \
    size_t ko = (size_t)(ks) * 64; \
    gload16(Ab + asrc[0] + ko, Ls[s3] + ad0); \
    gload16(Ab + asrc[1] + ko, Ls[s3] + ad1); \
    gload16(Bb + bsrc + ko, Ls[s3] + bd); }

  f32x4 acc[4][4] = {};
  const int awb = (wid >> 1) * 4096;            // wave's A tiles (4 x 1KB)
  const int bwb = 16384 + (wid & 1) * 4096;     // wave's B tiles (4 x 1KB)
  const int NS = K >> 5;                        // BK=32 slots (>= 3)
  STAGE(0,0) STAGE(1,1)                         // 6 loads in flight
  int cur = 0;
  for (int s = 0; s < NS; ++s){
    if (s + 1 < NS) { asm volatile("s_waitcnt vmcnt(3)" ::: "memory"); }
    else            { asm volatile("s_waitcnt vmcnt(0)" ::: "memory"); }
    __builtin_amdgcn_s_barrier();               // slot s in LDS; slot s-1 consumed
    __builtin_amdgcn_sched_barrier(0);
    if (s + 2 < NS){
      int sp = cur + 2; if (sp >= 3) sp -= 3;   // == (s-1)%3, freed at s-1
      STAGE(sp, s+2)
    }
    const char* base = Ls[cur];
    bf16x8 af[4], bfr[4];
#pragma unroll
    for (int i=0;i<4;i++) af[i]  = *(const bf16x8*)(base + awb + i*1024 + lane*16);
#pragma unroll
    for (int i=0;i<4;i++) bfr[i] = *(const bf16x8*)(base + bwb + i*1024 + lane*16);
    asm volatile("s_waitcnt lgkmcnt(0)" ::: "memory");
    __builtin_amdgcn_sched_barrier(0);
    __builtin_amdgcn_s_setprio(1);
#pragma unroll
    for (int mr=0;mr<4;mr++)
#pragma unroll
      for (int nc=0;nc<4;nc++)
        acc[mr][nc] = __builtin_amdgcn_mfma_f32_16x16x32_bf16(af[mr], bfr[nc], acc[mr][nc], 0,0,0);
    __builtin_amdgcn_s_setprio(0);
    cur = (cur + 1 == 3) ? 0 : cur + 1;
  }
#undef STAGE
  const int wm = (wid >> 1) * 64, wn = (wid & 1) * 64;
  if (m0 + 256 <= M){
#pragma unroll
    for (int mr=0;mr<4;mr++){
#pragma unroll
      for (int nc=0;nc<4;nc++){
#pragma unroll
        for (int rg=0;rg<4;rg++){
          int row = m0 + wm + mr*16 + ((lane>>4)<<2) + rg;
          int col = n0 + wn + nc*16 + (lane&15);
          float v = acc[mr][nc][rg];
          if (FOUT) Cf[(size_t)row*N + col] = v + bias[col];
          else      Cb[(size_t)row*N + col] = f2b(v);
        }
      }
    }
  } else {
#pragma unroll
    for (int mr=0;mr<4;mr++){
#pragma unroll
      for (int nc=0;nc<4;nc++){
#pragma unroll
        for (int rg=0;rg<4;rg++){
          int row = m0 + wm + mr*16 + ((lane>>4)<<2) + rg;
          int col = n0 + wn + nc*16 + (lane&15);
          if (row < M){
            float v = acc[mr][nc][rg];
            if (FOUT) Cf[(size_t)row*N + col] = v + bias[col];
            else      Cb[(size_t)row*N + col] = f2b(v);
          }
        }
      }
    }
  }
}

// ---- merged attention: agent split-K (bid<1024) + frame (bid>=1024) ----
// agent: grid slice 1024 = (bh 64) x (split 16); 5 waves (one per query t).
// frame: 3136 blocks = 8 b x 392; 320 threads = 320 (row,head) tasks each.
__global__ __launch_bounds__(320) void k_attn(
    const u16* __restrict__ out1, const float* __restrict__ aqkv,
    const float* __restrict__ mask,
    float* __restrict__ pm, float* __restrict__ pl, float* __restrict__ pacc,
    u16* __restrict__ IN)
{
  __shared__ __align__(16) char smem[32768];
  const int bid = blockIdx.x, tid = threadIdx.x;
  if (bid < 1024){
    char* Ksm = smem;            // 128 keys x 64 bf16, XOR-swizzled
    char* Vsm = smem + 16384;
    const int sp = bid & 15, bh = bid >> 4, b = bh >> 3, h = bh & 7;
    const int wid = tid >> 6, lane = tid & 63;
    const int q = wid;                           // query t index 0..4
    float qreg[64];
    {
      const float* ap = aqkv + ((size_t)(b*5+q)*1536 + h*64);
#pragma unroll
      for (int d=0; d<64; d++) qreg[d] = ap[d];
    }
    float m = -1e30f, l = 0.f;
    float acc[8] = {0,0,0,0,0,0,0,0};
    const int g0 = sp * 980;                     // 15680/16 keys per split
    for (int c = 0; c < 8; c++){                 // 7*128 + 84 = 980
      for (int idx = tid; idx < 2048; idx += 320){
        int r = idx >> 4, g = idx & 15;          // 16 granules = K(8)|V(8) per key
        int loc = c*128 + r; if (loc > 979) loc = 979;
        int gk = g0 + loc;
        int tk = gk / 3136, nv = gk - tk*3136;
        size_t grow = (size_t)((b*5+tk)*3137 + 1 + nv)*1536 + 512 + h*128 + g*8;
        u16x8 v = *(const u16x8*)(out1 + grow);
        char* dst = (g < 8) ? Ksm : Vsm;
        int seg = g & 7;
        *(u16x8*)(dst + r*128 + ((seg*16) ^ ((r&7)<<4))) = v;
      }
      __syncthreads();
      float s0 = 0.f, s1 = 0.f;
#pragma unroll
      for (int seg=0; seg<8; seg++){
        const int r0 = lane, r1 = 64 + lane;
        u16x8 k0 = *(const u16x8*)(Ksm + r0*128 + ((seg*16) ^ ((r0&7)<<4)));
        u16x8 k1 = *(const u16x8*)(Ksm + r1*128 + ((seg*16) ^ ((r1&7)<<4)));
#pragma unroll
        for (int j=0;j<8;j++){
          s0 += qreg[seg*8+j]*b2f(k0[j]);
          s1 += qreg[seg*8+j]*b2f(k1[j]);
        }
      }
      s0 *= 0.125f; s1 *= 0.125f;
      const int locbase = c*128;
      if (locbase + lane >= 980)      s0 = -1e30f;
      if (locbase + 64 + lane >= 980) s1 = -1e30f;
      float cmax = wred_max(fmaxf(s0, s1));
      float mn = fmaxf(m, cmax);
      float resc = __expf(m - mn);
      float p0 = (s0 > -1e29f) ? __expf(s0 - mn) : 0.f;
      float p1 = (s1 > -1e29f) ? __expf(s1 - mn) : 0.f;
      l = l*resc + wred_sum(p0 + p1);
#pragma unroll
      for (int j=0;j<8;j++) acc[j] *= resc;
      const int g = lane >> 3, cc = lane & 7;
#pragma unroll
      for (int i=0;i<16;i++){
        int k = i*8 + g;
        u16x8 vv = *(const u16x8*)(Vsm + k*128 + ((cc*16) ^ ((k&7)<<4)));
        float p = (i < 8) ? __shfl(p0, k) : __shfl(p1, k-64);
#pragma unroll
        for (int j=0;j<8;j++) acc[j] += p*b2f(vv[j]);
      }
      m = mn;
      __syncthreads();
    }
#pragma unroll
    for (int j=0;j<8;j++){
      float v = acc[j];
      v += __shfl_xor(v, 8); v += __shfl_xor(v, 16); v += __shfl_xor(v, 32);
      acc[j] = v;
    }
    const int base = (bh*16 + sp)*5 + q;
    if (lane == 0){ pm[base] = m; pl[base] = l; }
    if (lane < 8){
      float* pa = pacc + (size_t)base*64 + lane*8;
#pragma unroll
      for (int j=0;j<8;j++) pa[j] = acc[j];
    }
  } else {
    // ---- frame attention (k=5) + mask -> v rows of IN ----
    float (*Ka)[8][68] = (float(*)[8][68])smem;            // 10880 B
    float (*Va)[8][68] = (float(*)[8][68])(smem + 10880);  // 10880 B
    const int fid = bid - 1024;
    const int b = fid / 392, bx = fid % 392;
    for (int i = tid; i < 2560; i += 320){
      int t = i >> 9, rem = i & 511, hh = rem >> 6, d = rem & 63;
      const float* src = aqkv + (size_t)(b*5+t)*1536;
      Ka[t][hh][d] = src[512 + hh*64 + d];
      Va[t][hh][d] = src[1024 + hh*64 + d];
    }
    __syncthreads();
    const int task = bx*320 + tid;   // 0..125439 within b
    const int h = task & 7, rl = task >> 3;
    const int f = rl / 3136, nv = rl - f*3136;
    const int bt = b*5 + f;
    const size_t r1 = (size_t)bt*3137 + 1 + nv;
    u16* op = IN + r1*512 + h*64;
    const float mraw = mask[(size_t)bt*3136 + nv];
    if (mraw == 0.f){
      // masked row: skip vq load + math entirely
      u16x8 z = {};
#pragma unroll
      for (int sg=0; sg<8; sg++) *(u16x8*)(op + sg*8) = z;
    } else {
      const u16* qp = out1 + r1*1536 + h*64;   // vq slice (cols 0-512 of out1)
      float qf[64];
#pragma unroll
      for (int sg=0; sg<8; sg++){
        u16x8 v = *(const u16x8*)(qp + sg*8);
#pragma unroll
        for (int j=0;j<8;j++) qf[sg*8+j] = b2f(v[j]);
      }
      float sd[5];
#pragma unroll
      for (int t=0;t<5;t++){
        float s = 0.f;
#pragma unroll
        for (int d=0;d<64;d++) s += qf[d]*Ka[t][h][d];
        sd[t] = s*0.125f;
      }
      float mx = sd[0];
#pragma unroll
      for (int t=1;t<5;t++) mx = fmaxf(mx, sd[t]);
      float p[5], ps = 0.f;
#pragma unroll
      for (int t=0;t<5;t++){ p[t] = __expf(sd[t]-mx); ps += p[t]; }
      const float mv = mraw / ps;   // fold mask into normalizer
#pragma unroll
      for (int sg=0; sg<8; sg++){
        u16x8 o;
#pragma unroll
        for (int j=0;j<8;j++){
          const int d = sg*8+j;
          float v = 0.f;
#pragma unroll
          for (int t=0;t<5;t++) v += p[t]*Va[t][h][d];
          o[j] = f2b(v*mv);
        }
        *(u16x8*)(op + sg*8) = o;
      }
    }
  }
}

// ---------------- combine split-K partials -> agent rows of IN ----------------
__global__ void k_combine(const float* __restrict__ pm, const float* __restrict__ pl,
                          const float* __restrict__ pacc, u16* __restrict__ IN)
{
  const int id = blockIdx.x;   // 320 = b*8h*5q
  const int q = id % 5, t2 = id / 5;
  const int h = t2 & 7, b = t2 >> 3;
  const int d = threadIdx.x;   // 64
  const int bh = b*8 + h;
  float ms = -1e30f;
#pragma unroll
  for (int s2=0;s2<16;s2++) ms = fmaxf(ms, pm[(bh*16+s2)*5+q]);
  float L = 0.f, o = 0.f;
#pragma unroll
  for (int s2=0;s2<16;s2++){
    int base = (bh*16+s2)*5+q;
    float w = __expf(pm[base]-ms);
    L += w*pl[base];
    o += w*pacc[(size_t)base*64 + d];
  }
  IN[(size_t)(b*5+q)*3137*512 + h*64 + d] = f2b(o / L);
}

extern "C" void kernel_launch(void* const* d_in, const int* in_sizes, int n_in,
                              void* d_out, int out_size, void* d_ws, size_t ws_size,
                              hipStream_t stream)
{
  const float* x      = (const float*)d_in[0];
  const float* mask   = (const float*)d_in[1];
  const float* w_vq   = (const float*)d_in[2];
  const float* w_vkv  = (const float*)d_in[3];
  const float* w_aqkv = (const float*)d_in[4];
  const float* w_out  = (const float*)d_in[5];
  const float* b_out  = (const float*)d_in[6];
  float* out = (float*)d_out;
  char* ws = (char*)d_ws;

  constexpr size_t MR = 125480;                          // 40*3137
  constexpr size_t OFF_XB   = 0;                         // M x 512 bf16 (GEMM1 A; later IN)
  constexpr size_t OFF_OUT1 = OFF_XB + MR*512*2;         // M x 1536 bf16 (vq | per-head kv)
  constexpr size_t OFF_W1T  = OFF_OUT1 + MR*1536*2;      // 1536x512 bf16 (permuted cols)
  constexpr size_t OFF_WOT  = OFF_W1T + 1536*512*2;      // 512x512 bf16
  constexpr size_t OFF_AQKV = OFF_WOT + 512*512*2;       // 40x1536 f32
  constexpr size_t OFF_PM   = OFF_AQKV + 40*1536*4;      // 5120 f32
  constexpr size_t OFF_PL   = OFF_PM + 5120*4;           // 5120 f32
  constexpr size_t OFF_PACC = OFF_PL + 5120*4;           // 5120*64 f32

  u16* Xb     = (u16*)(ws + OFF_XB);
  u16* out1   = (u16*)(ws + OFF_OUT1);
  u16* W1T    = (u16*)(ws + OFF_W1T);
  u16* WoutT  = (u16*)(ws + OFF_WOT);
  float* aqkv = (float*)(ws + OFF_AQKV);
  float* pm   = (float*)(ws + OFF_PM);
  float* pl   = (float*)(ws + OFF_PL);
  float* pacc = (float*)(ws + OFF_PACC);

  k_pre<<<6384, 256, 0, stream>>>(x, w_vq, w_vkv, w_out, w_aqkv, Xb, W1T, WoutT, aqkv);
  k_gemm<0><<<5892, 512, 0, stream>>>(Xb, W1T, (int)MR, 1536, 512, 12,
                                      out1, nullptr, nullptr);
  k_attn<<<4160, 320, 0, stream>>>(out1, aqkv, mask, pm, pl, pacc, Xb);
  k_combine<<<320, 64, 0, stream>>>(pm, pl, pacc, Xb);
  k_gemm<1><<<1964, 512, 0, stream>>>(Xb, WoutT, (int)MR, 512, 512, 4,
                                      nullptr, out, b_out);
}

// Round 16
// 783.394 us; speedup vs baseline: 1.0976x; 1.0976x over previous
//
#include <hip/hip_runtime.h>

typedef unsigned short u16;
typedef unsigned int u32;
typedef __attribute__((ext_vector_type(8))) u16 u16x8;
typedef __attribute__((ext_vector_type(8))) __bf16 bf16x8;
typedef __attribute__((ext_vector_type(4))) float f32x4;

__device__ __forceinline__ float b2f(u16 u){ return __uint_as_float(((u32)u)<<16); }
__device__ __forceinline__ u16 f2b(float f){
  u32 b = __float_as_uint(f);
  return (u16)((b + 0x7fffu + ((b>>16)&1u))>>16);
}
__device__ __forceinline__ void gload16(const void* g, void* l){
  __builtin_amdgcn_global_load_lds((__attribute__((address_space(1))) void*)g,
                                   (__attribute__((address_space(3))) void*)l, 16, 0, 0);
}
__device__ __forceinline__ float wred_max(float v){
#pragma unroll
  for (int o=32;o>0;o>>=1) v = fmaxf(v, __shfl_xor(v,o));
  return v;
}
__device__ __forceinline__ float wred_sum(float v){
#pragma unroll
  for (int o=32;o>0;o>>=1) v += __shfl_xor(v,o);
  return v;
}

// ======================= measured-best configuration (r13, 784us) ==========
// Plateau evidence (7 GEMM structures, all 293-354us, MfmaUtil 17-30%,
// HBM <=26%): the r7 256^2 4-slot counted-vmcnt ring is the best expressible
// structure here; occupancy/tile/depth variations do not move it.
// Key layout trick: W1T columns permuted so out1 = [vq(512) | per-head
// (vk64|vv64) chunks] -- agent attention reads dense 256B chunks at zero
// GEMM cost (store pattern unchanged, WRITE=376MB ideal).
// Do-not-reintroduce list (measured): nt-stores (2x write amp, r4),
// routed/head-major epilogue (+60us / 1.6x write amp, r11/r12),
// per-lane routing branch (+78us, r11), frame-attn fused in epilogue
// (+196us, r10), BK=32 depth-1 128^2 (r9), 256x128 2-blk/CU (r15).

// out1 column order (set by W1T permutation in k_pre):
//   [0,512)   : vq (original order)
//   512+h*128 : head h's vk(64) | vv(64)  -- K+V contiguous 256B per key row

// ---- fused preprocessing: cast x -> bf16 | weight transposes | agent qkv ----
// grid 6384 x 256: [0,2048) cast, [2048,6144) prep_w, [6144,6384) agent qkv
__global__ void k_pre(const float* __restrict__ x, const float* __restrict__ wvq,
                      const float* __restrict__ wvkv, const float* __restrict__ wout,
                      const float* __restrict__ waqkv,
                      u16* __restrict__ xb, u16* __restrict__ W1T,
                      u16* __restrict__ WoutT, float* __restrict__ aqkv){
  const int bid = blockIdx.x, tid = threadIdx.x;
  if (bid < 2048){
    const int stride = 2048*256;
    for (int i = bid*256 + tid; i < 8030720; i += stride){
      const float4* p = (const float4*)(x + (size_t)i*8);
      float4 a = p[0], b = p[1];
      u16x8 o;
      o[0]=f2b(a.x); o[1]=f2b(a.y); o[2]=f2b(a.z); o[3]=f2b(a.w);
      o[4]=f2b(b.x); o[5]=f2b(b.y); o[6]=f2b(b.z); o[7]=f2b(b.w);
      *(u16x8*)(xb + (size_t)i*8) = o;
    }
  } else if (bid < 6144){
    int id = (bid-2048)*256 + tid;   // [0, 1048576)
    if (id < 786432){
      int n = id >> 9, k = id & 511;
      float v;
      if (n < 512){
        v = wvq[k*512 + n];
      } else {
        int j = n - 512, h = j >> 7, r = j & 127;
        int c2 = (r < 64) ? (h*64 + r) : (512 + h*64 + (r - 64));   // vk | vv
        v = wvkv[k*1024 + c2];
      }
      W1T[id] = f2b(v);
    } else {
      int j = id - 786432;
      int n = j >> 9, k = j & 511;
      WoutT[j] = f2b(wout[k*512 + n]);
    }
  } else {
    int id = (bid-6144)*256 + tid;   // [0, 61440)
    int bt = id / 1536, c = id % 1536;
    const float* xr = x + (size_t)bt*3137*512;
    float s = 0.f;
    for (int k=0;k<512;k++) s += xr[k]*waqkv[k*1536+c];
    aqkv[id] = s;
  }
}

// ---- 256x256 GEMM, 4-slot BK=32 ring, counted vmcnt (r7-proven, ~298us) ----
// A: MxK bf16 row-major, BT: NxK bf16 row-major. C = A * BT^T.
// Fragment-major LDS: every ds_read_b128 is uniform_base + lane*16 (0 conflicts).
// Single-buffer plain epilogue (WRITE=376MB ideal).
template<int FOUT>
__global__ __launch_bounds__(512, 2) void k_gemm256(
    const u16* __restrict__ A, const u16* __restrict__ BT,
    int M, int N, int K, int NX,
    u16* __restrict__ Cb, float* __restrict__ Cf, const float* __restrict__ bias)
{
  __shared__ __align__(16) char Ls[4][32768];   // slot: A 16KB | B 16KB
  const int tid = threadIdx.x;
  const int wid = tid >> 6, lane = tid & 63;
  // XCD-bijective swizzle (m204), n-fast work order (FETCH 512->81MB verified)
  const int nwg = gridDim.x, orig = blockIdx.x;
  const int q8 = nwg >> 3, r8 = nwg & 7;
  const int xc = orig & 7, sl = orig >> 3;
  const int work = (xc < r8 ? xc*(q8+1) : r8*(q8+1) + (xc-r8)*q8) + sl;
  const int m0 = (work / NX) * 256, n0 = (work % NX) * 256;
  const size_t K2 = (size_t)K * 2;
  const char* Ab = (const char*)A;
  const char* Bb = (const char*)BT;
  size_t asrc[2], bsrc[2];
  const int ad0 = wid*1024, ad1 = 8192 + wid*1024;  // wave-uniform LDS dest bases
#pragma unroll
  for (int i=0;i<2;i++){
    int row = (i*8 + wid)*16 + (lane & 15);
    int koff = (lane >> 4) << 4;
    int ra = m0 + row; if (ra >= M) ra = M - 1;   // clamp partial last M-tile
    asrc[i] = (size_t)ra * K2 + koff;
    bsrc[i] = (size_t)(n0 + row) * K2 + koff;     // N multiple of 256
  }
#define STAGE(s4, ks) { \
    size_t ko = (size_t)(ks) * 64; \
    gload16(Ab + asrc[0] + ko, Ls[s4] + ad0); \
    gload16(Ab + asrc[1] + ko, Ls[s4] + ad1); \
    gload16(Bb + bsrc[0] + ko, Ls[s4] + 16384 + ad0); \
    gload16(Bb + bsrc[1] + ko, Ls[s4] + 16384 + ad1); }

  f32x4 acc[8][4] = {};
  const int awb = (wid >> 2) * 8192;            // wave's A tiles (8 x 1KB)
  const int bwb = 16384 + (wid & 3) * 4096;     // wave's B tiles (4 x 1KB)
  const int NS = K >> 5;                        // BK=32 slots
  STAGE(0,0) STAGE(1,1) STAGE(2,2)              // 12 loads in flight
  for (int s = 0; s < NS; ++s){
    if (s + 2 < NS)      { asm volatile("s_waitcnt vmcnt(8)" ::: "memory"); }
    else if (s + 1 < NS) { asm volatile("s_waitcnt vmcnt(4)" ::: "memory"); }
    else                 { asm volatile("s_waitcnt vmcnt(0)" ::: "memory"); }
    __builtin_amdgcn_s_barrier();               // slot s in LDS; slot s-1 consumed
    __builtin_amdgcn_sched_barrier(0);
    if (s + 3 < NS) STAGE((s+3)&3, s+3)         // into pos freed at s-1
    const char* base = Ls[s & 3];
    bf16x8 af[8], bfr[4];
#pragma unroll
    for (int i=0;i<4;i++) af[i]  = *(const bf16x8*)(base + awb + i*1024 + lane*16);
#pragma unroll
    for (int i=0;i<4;i++) bfr[i] = *(const bf16x8*)(base + bwb + i*1024 + lane*16);
    asm volatile("s_waitcnt lgkmcnt(0)" ::: "memory");
    __builtin_amdgcn_sched_barrier(0);
    __builtin_amdgcn_s_setprio(1);
#pragma unroll
    for (int mr=0;mr<4;mr++)
#pragma unroll
      for (int nc=0;nc<4;nc++)
        acc[mr][nc] = __builtin_amdgcn_mfma_f32_16x16x32_bf16(af[mr], bfr[nc], acc[mr][nc], 0,0,0);
    __builtin_amdgcn_s_setprio(0);
#pragma unroll
    for (int i=4;i<8;i++) af[i] = *(const bf16x8*)(base + awb + i*1024 + lane*16);
    asm volatile("s_waitcnt lgkmcnt(0)" ::: "memory");
    __builtin_amdgcn_sched_barrier(0);
    __builtin_amdgcn_s_setprio(1);
#pragma unroll
    for (int mr=4;mr<8;mr++)
#pragma unroll
      for (int nc=0;nc<4;nc++)
        acc[mr][nc] = __builtin_amdgcn_mfma_f32_16x16x32_bf16(af[mr], bfr[nc], acc[mr][nc], 0,0,0);
    __builtin_amdgcn_s_setprio(0);
  }
#undef STAGE
  const int wm = (wid >> 2) * 128, wn = (wid & 3) * 64;
  if (m0 + 256 <= M){
#pragma unroll
    for (int mr=0;mr<8;mr++){
#pragma unroll
      for (int nc=0;nc<4;nc++){
#pragma unroll
        for (int rg=0;rg<4;rg++){
          int row = m0 + wm + mr*16 + ((lane>>4)<<2) + rg;
          int col = n0 + wn + nc*16 + (lane&15);
          float v = acc[mr][nc][rg];
          if (FOUT) Cf[(size_t)row*N + col] = v + bias[col];
          else      Cb[(size_t)row*N + col] = f2b(v);
        }
      }
    }
  } else {
#pragma unroll
    for (int mr=0;mr<8;mr++){
#pragma unroll
      for (int nc=0;nc<4;nc++){
#pragma unroll
        for (int rg=0;rg<4;rg++){
          int row = m0 + wm + mr*16 + ((lane>>4)<<2) + rg;
          int col = n0 + wn + nc*16 + (lane&15);
          if (row < M){
            float v = acc[mr][nc][rg];
            if (FOUT) Cf[(size_t)row*N + col] = v + bias[col];
            else      Cb[(size_t)row*N + col] = f2b(v);
          }
        }
      }
    }
  }
}

// ---------------- agent attention: softmax over 15680 keys, split-K=16 ----------------
// grid 1024 = (bh 64) x (split 16); block 320 = 5 waves (one per query t)
// out1 per-head K/V chunks: cols 512+h*128 = [vk64|vv64] -> staging reads one
// DENSE 256B chunk per key (16 consecutive lanes), 4 full lines, no waste.
__global__ __launch_bounds__(320) void k_attn_agent(
    const u16* __restrict__ out1, const float* __restrict__ aqkv,
    float* __restrict__ pm, float* __restrict__ pl, float* __restrict__ pacc)
{
  __shared__ __align__(16) char Ksm[16384];   // 128 keys x 64 bf16, XOR-swizzled
  __shared__ __align__(16) char Vsm[16384];
  const int bid = blockIdx.x;
  const int sp = bid & 15, bh = bid >> 4, b = bh >> 3, h = bh & 7;
  const int tid = threadIdx.x, wid = tid >> 6, lane = tid & 63;
  const int q = wid;                           // query t index 0..4
  float qreg[64];
  {
    const float* ap = aqkv + ((size_t)(b*5+q)*1536 + h*64);
#pragma unroll
    for (int d=0; d<64; d++) qreg[d] = ap[d];
  }
  float m = -1e30f, l = 0.f;
  float acc[8] = {0,0,0,0,0,0,0,0};
  const int g0 = sp * 980;                     // 15680/16 keys per split
  for (int c = 0; c < 8; c++){                 // 7*128 + 84 = 980
    for (int idx = tid; idx < 2048; idx += 320){
      int r = idx >> 4, g = idx & 15;          // 16 granules = K(8)|V(8) per key
      int loc = c*128 + r; if (loc > 979) loc = 979;
      int gk = g0 + loc;
      int tk = gk / 3136, nv = gk - tk*3136;
      size_t grow = (size_t)((b*5+tk)*3137 + 1 + nv)*1536 + 512 + h*128 + g*8;
      u16x8 v = *(const u16x8*)(out1 + grow);
      char* dst = (g < 8) ? Ksm : Vsm;
      int seg = g & 7;
      *(u16x8*)(dst + r*128 + ((seg*16) ^ ((r&7)<<4))) = v;
    }
    __syncthreads();
    float s0 = 0.f, s1 = 0.f;
#pragma unroll
    for (int seg=0; seg<8; seg++){
      const int r0 = lane, r1 = 64 + lane;
      u16x8 k0 = *(const u16x8*)(Ksm + r0*128 + ((seg*16) ^ ((r0&7)<<4)));
      u16x8 k1 = *(const u16x8*)(Ksm + r1*128 + ((seg*16) ^ ((r1&7)<<4)));
#pragma unroll
      for (int j=0;j<8;j++){
        s0 += qreg[seg*8+j]*b2f(k0[j]);
        s1 += qreg[seg*8+j]*b2f(k1[j]);
      }
    }
    s0 *= 0.125f; s1 *= 0.125f;
    const int locbase = c*128;
    if (locbase + lane >= 980)      s0 = -1e30f;
    if (locbase + 64 + lane >= 980) s1 = -1e30f;
    float cmax = wred_max(fmaxf(s0, s1));
    float mn = fmaxf(m, cmax);
    float resc = __expf(m - mn);
    float p0 = (s0 > -1e29f) ? __expf(s0 - mn) : 0.f;
    float p1 = (s1 > -1e29f) ? __expf(s1 - mn) : 0.f;
    l = l*resc + wred_sum(p0 + p1);
#pragma unroll
    for (int j=0;j<8;j++) acc[j] *= resc;
    const int g = lane >> 3, cc = lane & 7;
#pragma unroll
    for (int i=0;i<16;i++){
      int k = i*8 + g;
      u16x8 vv = *(const u16x8*)(Vsm + k*128 + ((cc*16) ^ ((k&7)<<4)));
      float p = (i < 8) ? __shfl(p0, k) : __shfl(p1, k-64);
#pragma unroll
      for (int j=0;j<8;j++) acc[j] += p*b2f(vv[j]);
    }
    m = mn;
    __syncthreads();
  }
#pragma unroll
  for (int j=0;j<8;j++){
    float v = acc[j];
    v += __shfl_xor(v, 8); v += __shfl_xor(v, 16); v += __shfl_xor(v, 32);
    acc[j] = v;
  }
  const int base = (bh*16 + sp)*5 + q;
  if (lane == 0){ pm[base] = m; pl[base] = l; }
  if (lane < 8){
    float* pa = pacc + (size_t)base*64 + lane*8;
#pragma unroll
    for (int j=0;j<8;j++) pa[j] = acc[j];
  }
}

// ---- frame attention (k=5)+mask -> v rows of IN; fused split-K combine -> a rows ----
// grid 4000 x 256: [0,3920) frame (490 per b), [3920,4000) combine (4 per block)
__global__ __launch_bounds__(256) void k_attn_frame(
    const u16* __restrict__ out1, const float* __restrict__ aqkv,
    const float* __restrict__ mask, const float* __restrict__ pm,
    const float* __restrict__ pl, const float* __restrict__ pacc,
    u16* __restrict__ IN)
{
  const int bid = blockIdx.x, tid = threadIdx.x;
  if (bid < 3920){
    __shared__ float Ka[5][8][68];
    __shared__ float Va[5][8][68];
    const int b = bid / 490, bx = bid % 490;
    for (int i = tid; i < 2560; i += 256){
      int t = i >> 9, rem = i & 511, hh = rem >> 6, d = rem & 63;
      const float* src = aqkv + (size_t)(b*5+t)*1536;
      Ka[t][hh][d] = src[512 + hh*64 + d];
      Va[t][hh][d] = src[1024 + hh*64 + d];
    }
    __syncthreads();
    const int task = bx*256 + tid;   // 0..125439
    const int h = task & 7, rl = task >> 3;
    const int f = rl / 3136, nv = rl - f*3136;
    const int bt = b*5 + f;
    const size_t r1 = (size_t)bt*3137 + 1 + nv;
    const u16* qp = out1 + r1*1536 + h*64;   // vq slice (cols 0-512 of out1)
    float qf[64];
#pragma unroll
    for (int sg=0; sg<8; sg++){
      u16x8 v = *(const u16x8*)(qp + sg*8);
#pragma unroll
      for (int j=0;j<8;j++) qf[sg*8+j] = b2f(v[j]);
    }
    float sd[5];
#pragma unroll
    for (int t=0;t<5;t++){
      float s = 0.f;
#pragma unroll
      for (int d=0;d<64;d++) s += qf[d]*Ka[t][h][d];
      sd[t] = s*0.125f;
    }
    float mx = sd[0];
#pragma unroll
    for (int t=1;t<5;t++) mx = fmaxf(mx, sd[t]);
    float p[5], ps = 0.f;
#pragma unroll
    for (int t=0;t<5;t++){ p[t] = __expf(sd[t]-mx); ps += p[t]; }
    const float mv = mask[(size_t)bt*3136 + nv] / ps;   // fold mask into normalizer
    u16* op = IN + r1*512 + h*64;
#pragma unroll
    for (int sg=0; sg<8; sg++){
      u16x8 o;
#pragma unroll
      for (int j=0;j<8;j++){
        const int d = sg*8+j;
        float v = 0.f;
#pragma unroll
        for (int t=0;t<5;t++) v += p[t]*Va[t][h][d];
        o[j] = f2b(v*mv);
      }
      *(u16x8*)(op + sg*8) = o;
    }
  } else {
    // combine: 4 (b,h,q) tasks per block, 64 lanes each over d
    const int id = (bid - 3920)*4 + (tid >> 6);   // [0,320)
    const int d = tid & 63;
    const int q = id % 5, t2 = id / 5;
    const int h = t2 & 7, b = t2 >> 3;
    const int bh = b*8 + h;
    float ms = -1e30f;
#pragma unroll
    for (int s2=0;s2<16;s2++) ms = fmaxf(ms, pm[(bh*16+s2)*5+q]);
    float L = 0.f, o = 0.f;
#pragma unroll
    for (int s2=0;s2<16;s2++){
      int base = (bh*16+s2)*5+q;
      float w = __expf(pm[base]-ms);
      L += w*pl[base];
      o += w*pacc[(size_t)base*64 + d];
    }
    IN[(size_t)(b*5+q)*3137*512 + h*64 + d] = f2b(o / L);
  }
}

extern "C" void kernel_launch(void* const* d_in, const int* in_sizes, int n_in,
                              void* d_out, int out_size, void* d_ws, size_t ws_size,
                              hipStream_t stream)
{
  const float* x      = (const float*)d_in[0];
  const float* mask   = (const float*)d_in[1];
  const float* w_vq   = (const float*)d_in[2];
  const float* w_vkv  = (const float*)d_in[3];
  const float* w_aqkv = (const float*)d_in[4];
  const float* w_out  = (const float*)d_in[5];
  const float* b_out  = (const float*)d_in[6];
  float* out = (float*)d_out;
  char* ws = (char*)d_ws;

  constexpr size_t MR = 125480;                          // 40*3137
  constexpr size_t OFF_XB   = 0;                         // M x 512 bf16 (GEMM1 A; later IN)
  constexpr size_t OFF_OUT1 = OFF_XB + MR*512*2;         // M x 1536 bf16 (vq | per-head kv)
  constexpr size_t OFF_W1T  = OFF_OUT1 + MR*1536*2;      // 1536x512 bf16 (permuted cols)
  constexpr size_t OFF_WOT  = OFF_W1T + 1536*512*2;      // 512x512 bf16
  constexpr size_t OFF_AQKV = OFF_WOT + 512*512*2;       // 40x1536 f32
  constexpr size_t OFF_PM   = OFF_AQKV + 40*1536*4;      // 5120 f32
  constexpr size_t OFF_PL   = OFF_PM + 5120*4;           // 5120 f32
  constexpr size_t OFF_PACC = OFF_PL + 5120*4;           // 5120*64 f32

  u16* Xb     = (u16*)(ws + OFF_XB);
  u16* out1   = (u16*)(ws + OFF_OUT1);
  u16* W1T    = (u16*)(ws + OFF_W1T);
  u16* WoutT  = (u16*)(ws + OFF_WOT);
  float* aqkv = (float*)(ws + OFF_AQKV);
  float* pm   = (float*)(ws + OFF_PM);
  float* pl   = (float*)(ws + OFF_PL);
  float* pacc = (float*)(ws + OFF_PACC);

  k_pre<<<6384, 256, 0, stream>>>(x, w_vq, w_vkv, w_out, w_aqkv, Xb, W1T, WoutT, aqkv);
  k_gemm256<0><<<2946, 512, 0, stream>>>(Xb, W1T, (int)MR, 1536, 512, 6,
                                         out1, nullptr, nullptr);
  k_attn_agent<<<1024, 320, 0, stream>>>(out1, aqkv, pm, pl, pacc);
  k_attn_frame<<<4000, 256, 0, stream>>>(out1, aqkv, mask, pm, pl, pacc, Xb);
  k_gemm256<1><<<982, 512, 0, stream>>>(Xb, WoutT, (int)MR, 512, 512, 2,
                                        nullptr, out, b_out);
}

// Round 17
// 774.630 us; speedup vs baseline: 1.1100x; 1.0113x over previous
//
#include <hip/hip_runtime.h>

typedef unsigned short u16;
typedef unsigned int u32;
typedef __attribute__((ext_vector_type(8))) u16 u16x8;
typedef __attribute__((ext_vector_type(8))) __bf16 bf16x8;
typedef __attribute__((ext_vector_type(4))) float f32x4;

__device__ __forceinline__ float b2f(u16 u){ return __uint_as_float(((u32)u)<<16); }
__device__ __forceinline__ u16 f2b(float f){
  u32 b = __float_as_uint(f);
  return (u16)((b + 0x7fffu + ((b>>16)&1u))>>16);
}
__device__ __forceinline__ void gload16(const void* g, void* l){
  __builtin_amdgcn_global_load_lds((__attribute__((address_space(1))) void*)g,
                                   (__attribute__((address_space(3))) void*)l, 16, 0, 0);
}
__device__ __forceinline__ float wred_max(float v){
#pragma unroll
  for (int o=32;o>0;o>>=1) v = fmaxf(v, __shfl_xor(v,o));
  return v;
}
__device__ __forceinline__ float wred_sum(float v){
#pragma unroll
  for (int o=32;o>0;o>>=1) v += __shfl_xor(v,o);
  return v;
}

// out1 column order (set by W1T permutation in k_pre):
//   [0,512)   : vq (original order)
//   512+h*128 : head h's vk(64) | vv(64)  -- K+V contiguous 256B per key row

// ---- fused preprocessing: cast x -> bf16 | weight transposes | agent qkv ----
__global__ void k_pre(const float* __restrict__ x, const float* __restrict__ wvq,
                      const float* __restrict__ wvkv, const float* __restrict__ wout,
                      const float* __restrict__ waqkv,
                      u16* __restrict__ xb, u16* __restrict__ W1T,
                      u16* __restrict__ WoutT, float* __restrict__ aqkv){
  const int bid = blockIdx.x, tid = threadIdx.x;
  if (bid < 2048){
    const int stride = 2048*256;
    for (int i = bid*256 + tid; i < 8030720; i += stride){
      const float4* p = (const float4*)(x + (size_t)i*8);
      float4 a = p[0], b = p[1];
      u16x8 o;
      o[0]=f2b(a.x); o[1]=f2b(a.y); o[2]=f2b(a.z); o[3]=f2b(a.w);
      o[4]=f2b(b.x); o[5]=f2b(b.y); o[6]=f2b(b.z); o[7]=f2b(b.w);
      *(u16x8*)(xb + (size_t)i*8) = o;
    }
  } else if (bid < 6144){
    int id = (bid-2048)*256 + tid;
    if (id < 786432){
      int n = id >> 9, k = id & 511;
      float v;
      if (n < 512){
        v = wvq[k*512 + n];
      } else {
        int j = n - 512, h = j >> 7, r = j & 127;
        int c2 = (r < 64) ? (h*64 + r) : (512 + h*64 + (r - 64));   // vk | vv
        v = wvkv[k*1024 + c2];
      }
      W1T[id] = f2b(v);
    } else {
      int j = id - 786432;
      int n = j >> 9, k = j & 511;
      WoutT[j] = f2b(wout[k*512 + n]);
    }
  } else {
    int id = (bid-6144)*256 + tid;
    int bt = id / 1536, c = id % 1536;
    const float* xr = x + (size_t)bt*3137*512;
    float s = 0.f;
    for (int k=0;k<512;k++) s += xr[k]*waqkv[k*1536+c];
    aqkv[id] = s;
  }
}

// ======== 256x256 GEMM, 8-phase schedule (m201 template port) ========
// K_STEP=64 K-tiles; LDS 128KB = {A,B} x dbuf{0,1} x half{0,1} x [128r x 64k].
// 8 waves (wm=wid>>2, wn=wid&3). Wave reads ONE A-half (qm) + ONE B-half (qn)
// per phase; per-tile Gray quadrant order (0,0),(0,1),(1,1),(1,0).
// Fragment-major LDS halves: 8 tiles x 2KB (16 rows), tile = 2 k-blocks x 1KB,
// lane*16 -> (row=lane&15, k=kb*32+(lane>>4)*8): all ds_read_b128 conflict-free.
// Per-iteration (computes tiles t=2i -> buf0, t+1 -> buf1), stage ledger
// (1 half-tile = 2 gload16/thread per phase; target last READ 2 barriers prior):
//  p1: A1'(t+1)->b1 [lastRd prev p7]   p2: B0'(t+1)->b1 [prev p8]
//  p3: A0(t+2)->b0  [p1]               p4: B1(t+2)->b0  [p2]
//  p5: A1(t+2)->b0  [p3]               p6: B0(t+2)->b0  [p4]
//  p7: A0'(t+3)->b1 [p5]               p8: B1'(t+3)->b1 [p6]
// Gates (T4, never 0 mid-loop): end-p4 & end-p8 vmcnt(4) -> leaves exactly the
// 2 newest half-tiles in flight; everything the next 4 phases read has landed
// (hand-verified incl. prologue order A0(0),B1(0),A1(0),B0(0),A0(1),B1(1)).
// Phase body: reads; stage; barrier; lgkm0+sched_barrier (rule #18);
// setprio(1); 16 MFMA; setprio(0); [gate]; barrier.
template<int FOUT>
__global__ __launch_bounds__(512, 2) void k_gemm8p(
    const u16* __restrict__ A, const u16* __restrict__ BT,
    int M, int N, int K, int NX,
    u16* __restrict__ Cb, float* __restrict__ Cf, const float* __restrict__ bias)
{
  __shared__ __align__(16) char Ls[131072];
  char* LA = Ls;             // + d*32768 + h*16384
  char* LB = Ls + 65536;
  const int tid = threadIdx.x;
  const int wid = tid >> 6, lane = tid & 63;
  const int wm = wid >> 2, wn = wid & 3;
  // XCD-bijective swizzle (m204), n-fast work order
  const int nwg = gridDim.x, orig = blockIdx.x;
  const int q8 = nwg >> 3, r8 = nwg & 7;
  const int xc = orig & 7, sl = orig >> 3;
  const int work = (xc < r8 ? xc*(q8+1) : r8*(q8+1) + (xc-r8)*q8) + sl;
  const int m0 = (work / NX) * 256, n0 = (work % NX) * 256;
  const size_t K2 = (size_t)K * 2;
  const char* Ab = (const char*)A;
  const char* Bb = (const char*)BT;
  size_t asrch[2], bsrch[2];
#pragma unroll
  for (int h=0; h<2; h++){
    int ra = m0 + h*128 + wid*16 + (lane & 15);
    if (ra >= M) ra = M - 1;                       // clamp partial last M-tile
    asrch[h] = (size_t)ra * K2 + ((lane >> 4) << 4);
    bsrch[h] = (size_t)(n0 + h*128 + wid*16 + (lane & 15)) * K2 + ((lane >> 4) << 4);
  }
  const int sd0 = wid*2048;                        // wave-uniform LDS dest base

#define STG_A(d,h,kt) { size_t ko = (size_t)(kt)*128; \
    gload16(Ab + asrch[h] + ko,      LA + (d)*32768 + (h)*16384 + sd0); \
    gload16(Ab + asrch[h] + ko + 64, LA + (d)*32768 + (h)*16384 + sd0 + 1024); }
#define STG_B(d,h,kt) { size_t ko = (size_t)(kt)*128; \
    gload16(Bb + bsrch[h] + ko,      LB + (d)*32768 + (h)*16384 + sd0); \
    gload16(Bb + bsrch[h] + ko + 64, LB + (d)*32768 + (h)*16384 + sd0 + 1024); }

  bf16x8 afr[4][2], bfr[2][2];
#define RD_A(d,QM) { const char* ab_ = LA + (d)*32768 + (QM)*16384 + wm*8192 + lane*16; \
    _Pragma("unroll") for (int fm=0; fm<4; fm++){ \
      afr[fm][0] = *(const bf16x8*)(ab_ + fm*2048); \
      afr[fm][1] = *(const bf16x8*)(ab_ + fm*2048 + 1024); } }
#define RD_B(d,QN) { const char* bb_ = LB + (d)*32768 + (QN)*16384 + wn*4096 + lane*16; \
    _Pragma("unroll") for (int fn=0; fn<2; fn++){ \
      bfr[fn][0] = *(const bf16x8*)(bb_ + fn*2048); \
      bfr[fn][1] = *(const bf16x8*)(bb_ + fn*2048 + 1024); } }

  f32x4 acc[8][4] = {};
#define MFMA16(QM,QN) { \
    _Pragma("unroll") for (int fm=0; fm<4; fm++){ \
      _Pragma("unroll") for (int fn=0; fn<2; fn++){ \
        acc[(QM)*4+fm][(QN)*2+fn] = __builtin_amdgcn_mfma_f32_16x16x32_bf16( \
            afr[fm][0], bfr[fn][0], acc[(QM)*4+fm][(QN)*2+fn], 0,0,0); \
        acc[(QM)*4+fm][(QN)*2+fn] = __builtin_amdgcn_mfma_f32_16x16x32_bf16( \
            afr[fm][1], bfr[fn][1], acc[(QM)*4+fm][(QN)*2+fn], 0,0,0); } } }

#define PH_MID(QM,QN) \
    __builtin_amdgcn_sched_barrier(0); \
    __builtin_amdgcn_s_barrier(); \
    asm volatile("s_waitcnt lgkmcnt(0)" ::: "memory"); \
    __builtin_amdgcn_sched_barrier(0); \
    __builtin_amdgcn_s_setprio(1); \
    MFMA16(QM,QN) \
    __builtin_amdgcn_s_setprio(0); \
    __builtin_amdgcn_sched_barrier(0);
#define BAR __builtin_amdgcn_s_barrier()

  const int NI = K >> 7;                           // iterations (2 K-tiles each); K=512 -> 4
  // prologue: 6 half-tiles in steady-state issue order, then gate
  STG_A(0,0,0) STG_B(0,1,0) STG_A(0,1,0) STG_B(0,0,0) STG_A(1,0,1) STG_B(1,1,1)
  asm volatile("s_waitcnt vmcnt(4)" ::: "memory"); // tile 0 fully landed
  BAR;

  for (int it = 0; it < NI; ++it){
    const int t1 = 2*it + 1, t2 = 2*it + 2, t3 = 2*it + 3;
    const bool more = (it + 1 < NI);
    // p1: Q(0,0) of t
    RD_A(0,0) RD_B(0,0) STG_A(1,1,t1)
    PH_MID(0,0) BAR;
    // p2: Q(0,1)
    RD_B(0,1) STG_B(1,0,t1)
    PH_MID(0,1) BAR;
    // p3: Q(1,1)
    RD_A(0,1) if (more){ STG_A(0,0,t2) }
    PH_MID(1,1) BAR;
    // p4: Q(1,0) + K-tile gate
    RD_B(0,0) if (more){ STG_B(0,1,t2) }
    PH_MID(1,0)
    if (more) { asm volatile("s_waitcnt vmcnt(4)" ::: "memory"); }
    else      { asm volatile("s_waitcnt vmcnt(0)" ::: "memory"); }
    BAR;
    // p5: Q(0,0) of t+1
    RD_A(1,0) RD_B(1,0) if (more){ STG_A(0,1,t2) }
    PH_MID(0,0) BAR;
    // p6: Q(0,1)
    RD_B(1,1) if (more){ STG_B(0,0,t2) }
    PH_MID(0,1) BAR;
    // p7: Q(1,1)
    RD_A(1,1) if (more){ STG_A(1,0,t3) }
    PH_MID(1,1) BAR;
    // p8: Q(1,0) + K-tile gate
    RD_B(1,0) if (more){ STG_B(1,1,t3) }
    PH_MID(1,0)
    if (more) { asm volatile("s_waitcnt vmcnt(4)" ::: "memory"); }
    BAR;
  }
#undef STG_A
#undef STG_B
#undef RD_A
#undef RD_B
#undef MFMA16
#undef PH_MID
#undef BAR
  // epilogue: row = m0 + (mi>>2)*128 + wm*64 + (mi&3)*16 + (lane>>4)*4 + rg
  //           col = n0 + (ni>>1)*128 + wn*32 + (ni&1)*16 + (lane&15)
  // plain scalar stores (nt = 2x write amp r4; routed epilogues regress r11/r12)
  if (m0 + 256 <= M){
#pragma unroll
    for (int mi=0; mi<8; mi++){
      const int rb = m0 + (mi>>2)*128 + wm*64 + (mi&3)*16 + ((lane>>4)<<2);
#pragma unroll
      for (int ni=0; ni<4; ni++){
        const int col = n0 + (ni>>1)*128 + wn*32 + (ni&1)*16 + (lane&15);
#pragma unroll
        for (int rg=0; rg<4; rg++){
          float v = acc[mi][ni][rg];
          if (FOUT) Cf[(size_t)(rb+rg)*N + col] = v + bias[col];
          else      Cb[(size_t)(rb+rg)*N + col] = f2b(v);
        }
      }
    }
  } else {
#pragma unroll
    for (int mi=0; mi<8; mi++){
      const int rb = m0 + (mi>>2)*128 + wm*64 + (mi&3)*16 + ((lane>>4)<<2);
#pragma unroll
      for (int ni=0; ni<4; ni++){
        const int col = n0 + (ni>>1)*128 + wn*32 + (ni&1)*16 + (lane&15);
#pragma unroll
        for (int rg=0; rg<4; rg++){
          if (rb + rg < M){
            float v = acc[mi][ni][rg];
            if (FOUT) Cf[(size_t)(rb+rg)*N + col] = v + bias[col];
            else      Cb[(size_t)(rb+rg)*N + col] = f2b(v);
          }
        }
      }
    }
  }
}

// ---------------- agent attention: softmax over 15680 keys, split-K=16 ----------------
__global__ __launch_bounds__(320) void k_attn_agent(
    const u16* __restrict__ out1, const float* __restrict__ aqkv,
    float* __restrict__ pm, float* __restrict__ pl, float* __restrict__ pacc)
{
  __shared__ __align__(16) char Ksm[16384];   // 128 keys x 64 bf16, XOR-swizzled
  __shared__ __align__(16) char Vsm[16384];
  const int bid = blockIdx.x;
  const int sp = bid & 15, bh = bid >> 4, b = bh >> 3, h = bh & 7;
  const int tid = threadIdx.x, wid = tid >> 6, lane = tid & 63;
  const int q = wid;
  float qreg[64];
  {
    const float* ap = aqkv + ((size_t)(b*5+q)*1536 + h*64);
#pragma unroll
    for (int d=0; d<64; d++) qreg[d] = ap[d];
  }
  float m = -1e30f, l = 0.f;
  float acc[8] = {0,0,0,0,0,0,0,0};
  const int g0 = sp * 980;
  for (int c = 0; c < 8; c++){
    for (int idx = tid; idx < 2048; idx += 320){
      int r = idx >> 4, g = idx & 15;
      int loc = c*128 + r; if (loc > 979) loc = 979;
      int gk = g0 + loc;
      int tk = gk / 3136, nv = gk - tk*3136;
      size_t grow = (size_t)((b*5+tk)*3137 + 1 + nv)*1536 + 512 + h*128 + g*8;
      u16x8 v = *(const u16x8*)(out1 + grow);
      char* dst = (g < 8) ? Ksm : Vsm;
      int seg = g & 7;
      *(u16x8*)(dst + r*128 + ((seg*16) ^ ((r&7)<<4))) = v;
    }
    __syncthreads();
    float s0 = 0.f, s1 = 0.f;
#pragma unroll
    for (int seg=0; seg<8; seg++){
      const int r0 = lane, r1 = 64 + lane;
      u16x8 k0 = *(const u16x8*)(Ksm + r0*128 + ((seg*16) ^ ((r0&7)<<4)));
      u16x8 k1 = *(const u16x8*)(Ksm + r1*128 + ((seg*16) ^ ((r1&7)<<4)));
#pragma unroll
      for (int j=0;j<8;j++){
        s0 += qreg[seg*8+j]*b2f(k0[j]);
        s1 += qreg[seg*8+j]*b2f(k1[j]);
      }
    }
    s0 *= 0.125f; s1 *= 0.125f;
    const int locbase = c*128;
    if (locbase + lane >= 980)      s0 = -1e30f;
    if (locbase + 64 + lane >= 980) s1 = -1e30f;
    float cmax = wred_max(fmaxf(s0, s1));
    float mn = fmaxf(m, cmax);
    float resc = __expf(m - mn);
    float p0 = (s0 > -1e29f) ? __expf(s0 - mn) : 0.f;
    float p1 = (s1 > -1e29f) ? __expf(s1 - mn) : 0.f;
    l = l*resc + wred_sum(p0 + p1);
#pragma unroll
    for (int j=0;j<8;j++) acc[j] *= resc;
    const int g = lane >> 3, cc = lane & 7;
#pragma unroll
    for (int i=0;i<16;i++){
      int k = i*8 + g;
      u16x8 vv = *(const u16x8*)(Vsm + k*128 + ((cc*16) ^ ((k&7)<<4)));
      float p = (i < 8) ? __shfl(p0, k) : __shfl(p1, k-64);
#pragma unroll
      for (int j=0;j<8;j++) acc[j] += p*b2f(vv[j]);
    }
    m = mn;
    __syncthreads();
  }
#pragma unroll
  for (int j=0;j<8;j++){
    float v = acc[j];
    v += __shfl_xor(v, 8); v += __shfl_xor(v, 16); v += __shfl_xor(v, 32);
    acc[j] = v;
  }
  const int base = (bh*16 + sp)*5 + q;
  if (lane == 0){ pm[base] = m; pl[base] = l; }
  if (lane < 8){
    float* pa = pacc + (size_t)base*64 + lane*8;
#pragma unroll
    for (int j=0;j<8;j++) pa[j] = acc[j];
  }
}

// ---- frame attention (k=5)+mask -> v rows of IN; fused split-K combine -> a rows ----
__global__ __launch_bounds__(256) void k_attn_frame(
    const u16* __restrict__ out1, const float* __restrict__ aqkv,
    const float* __restrict__ mask, const float* __restrict__ pm,
    const float* __restrict__ pl, const float* __restrict__ pacc,
    u16* __restrict__ IN)
{
  const int bid = blockIdx.x, tid = threadIdx.x;
  if (bid < 3920){
    __shared__ float Ka[5][8][68];
    __shared__ float Va[5][8][68];
    const int b = bid / 490, bx = bid % 490;
    for (int i = tid; i < 2560; i += 256){
      int t = i >> 9, rem = i & 511, hh = rem >> 6, d = rem & 63;
      const float* src = aqkv + (size_t)(b*5+t)*1536;
      Ka[t][hh][d] = src[512 + hh*64 + d];
      Va[t][hh][d] = src[1024 + hh*64 + d];
    }
    __syncthreads();
    const int task = bx*256 + tid;
    const int h = task & 7, rl = task >> 3;
    const int f = rl / 3136, nv = rl - f*3136;
    const int bt = b*5 + f;
    const size_t r1 = (size_t)bt*3137 + 1 + nv;
    const u16* qp = out1 + r1*1536 + h*64;
    float qf[64];
#pragma unroll
    for (int sg=0; sg<8; sg++){
      u16x8 v = *(const u16x8*)(qp + sg*8);
#pragma unroll
      for (int j=0;j<8;j++) qf[sg*8+j] = b2f(v[j]);
    }
    float sd[5];
#pragma unroll
    for (int t=0;t<5;t++){
      float s = 0.f;
#pragma unroll
      for (int d=0;d<64;d++) s += qf[d]*Ka[t][h][d];
      sd[t] = s*0.125f;
    }
    float mx = sd[0];
#pragma unroll
    for (int t=1;t<5;t++) mx = fmaxf(mx, sd[t]);
    float p[5], ps = 0.f;
#pragma unroll
    for (int t=0;t<5;t++){ p[t] = __expf(sd[t]-mx); ps += p[t]; }
    const float mv = mask[(size_t)bt*3136 + nv] / ps;
    u16* op = IN + r1*512 + h*64;
#pragma unroll
    for (int sg=0; sg<8; sg++){
      u16x8 o;
#pragma unroll
      for (int j=0;j<8;j++){
        const int d = sg*8+j;
        float v = 0.f;
#pragma unroll
        for (int t=0;t<5;t++) v += p[t]*Va[t][h][d];
        o[j] = f2b(v*mv);
      }
      *(u16x8*)(op + sg*8) = o;
    }
  } else {
    const int id = (bid - 3920)*4 + (tid >> 6);
    const int d = tid & 63;
    const int q = id % 5, t2 = id / 5;
    const int h = t2 & 7, b = t2 >> 3;
    const int bh = b*8 + h;
    float ms = -1e30f;
#pragma unroll
    for (int s2=0;s2<16;s2++) ms = fmaxf(ms, pm[(bh*16+s2)*5+q]);
    float L = 0.f, o = 0.f;
#pragma unroll
    for (int s2=0;s2<16;s2++){
      int base = (bh*16+s2)*5+q;
      float w = __expf(pm[base]-ms);
      L += w*pl[base];
      o += w*pacc[(size_t)base*64 + d];
    }
    IN[(size_t)(b*5+q)*3137*512 + h*64 + d] = f2b(o / L);
  }
}

extern "C" void kernel_launch(void* const* d_in, const int* in_sizes, int n_in,
                              void* d_out, int out_size, void* d_ws, size_t ws_size,
                              hipStream_t stream)
{
  const float* x      = (const float*)d_in[0];
  const float* mask   = (const float*)d_in[1];
  const float* w_vq   = (const float*)d_in[2];
  const float* w_vkv  = (const float*)d_in[3];
  const float* w_aqkv = (const float*)d_in[4];
  const float* w_out  = (const float*)d_in[5];
  const float* b_out  = (const float*)d_in[6];
  float* out = (float*)d_out;
  char* ws = (char*)d_ws;

  constexpr size_t MR = 125480;                          // 40*3137
  constexpr size_t OFF_XB   = 0;                         // M x 512 bf16 (GEMM1 A; later IN)
  constexpr size_t OFF_OUT1 = OFF_XB + MR*512*2;         // M x 1536 bf16 (vq | per-head kv)
  constexpr size_t OFF_W1T  = OFF_OUT1 + MR*1536*2;      // 1536x512 bf16 (permuted cols)
  constexpr size_t OFF_WOT  = OFF_W1T + 1536*512*2;      // 512x512 bf16
  constexpr size_t OFF_AQKV = OFF_WOT + 512*512*2;       // 40x1536 f32
  constexpr size_t OFF_PM   = OFF_AQKV + 40*1536*4;      // 5120 f32
  constexpr size_t OFF_PL   = OFF_PM + 5120*4;           // 5120 f32
  constexpr size_t OFF_PACC = OFF_PL + 5120*4;           // 5120*64 f32

  u16* Xb     = (u16*)(ws + OFF_XB);
  u16* out1   = (u16*)(ws + OFF_OUT1);
  u16* W1T    = (u16*)(ws + OFF_W1T);
  u16* WoutT  = (u16*)(ws + OFF_WOT);
  float* aqkv = (float*)(ws + OFF_AQKV);
  float* pm   = (float*)(ws + OFF_PM);
  float* pl   = (float*)(ws + OFF_PL);
  float* pacc = (float*)(ws + OFF_PACC);

  k_pre<<<6384, 256, 0, stream>>>(x, w_vq, w_vkv, w_out, w_aqkv, Xb, W1T, WoutT, aqkv);
  k_gemm8p<0><<<2946, 512, 0, stream>>>(Xb, W1T, (int)MR, 1536, 512, 6,
                                        out1, nullptr, nullptr);
  k_attn_agent<<<1024, 320, 0, stream>>>(out1, aqkv, pm, pl, pacc);
  k_attn_frame<<<4000, 256, 0, stream>>>(out1, aqkv, mask, pm, pl, pacc, Xb);
  k_gemm8p<1><<<982, 512, 0, stream>>>(Xb, WoutT, (int)MR, 512, 512, 2,
                                       nullptr, out, b_out);
}